// Round 16
// baseline (435.970 us; speedup 1.0000x reference)
//
#include <hip/hip_runtime.h>
#include <hip/hip_bf16.h>

typedef _Float16 h16;
typedef _Float16 h16x8 __attribute__((ext_vector_type(8)));
typedef _Float16 h16x4 __attribute__((ext_vector_type(4)));
typedef float    f32x4 __attribute__((ext_vector_type(4)));
typedef unsigned int u32x4 __attribute__((ext_vector_type(4)));

#define MFMA(a,b,c) __builtin_amdgcn_mfma_f32_16x16x32_f16((a),(b),(c),0,0,0)

// H=2 B=64 LT=384 LI=128 L=512 D=768 K=V=384 DK=DV=768 LQ=24
// Tiled layouts (MFMA-native):
//  Q,K:  [hb][ks=12][row=512][d32]; V: [hb][kt=16][vcol=384][k32]
//  keys: [b][ks=24][key=512][d32];  vals: [b][kt=16][vcol=768][k32]

typedef __attribute__((address_space(1))) const void gas_void;
typedef __attribute__((address_space(3))) void las_void;
__device__ __forceinline__ void gld16(void* l, const void* g) {
  __builtin_amdgcn_global_load_lds((gas_void*)g, (las_void*)l, 16, 0, 0);
}
__device__ __forceinline__ void ntst16(void* p, const void* v) {
  __builtin_nontemporal_store(*(const u32x4*)v, (u32x4*)p);
}

__global__ __launch_bounds__(256) void k_diag(float* out, int n, float val) {
  int i = blockIdx.x * 256 + threadIdx.x;
  if (i < n) out[i] = val;
}

// ---------------- FUSED prep: weight transposes (bid<4608) + LayerNorm (rest)
__global__ __launch_bounds__(256) void k_prep(
    const float* __restrict__ Wsq, const float* __restrict__ Wiq,
    const float* __restrict__ Wsk, const float* __restrict__ Wik,
    const float* __restrict__ Wsv, const float* __restrict__ Wiv,
    const float* __restrict__ Wkp, const float* __restrict__ Wvp,
    h16* __restrict__ wb,
    const float* __restrict__ text, const float* __restrict__ images,
    const float* __restrict__ g, const float* __restrict__ be,
    h16* __restrict__ xn,
    const int* __restrict__ tlen, const int* __restrict__ ilen)
{
  const size_t WSZ = 589824;
  int bid = blockIdx.x;
  if (bid < 4608) {
    const float* src; h16* dst;
    int cols, cx, cy;
    if (bid < 3456) {
      int z = bid / 288, rem = bid % 288;
      cx = rem % 12; cy = rem / 12;
      int w = z >> 1, m = z & 1;
      const float* s6[6] = {Wsq, Wiq, Wsk, Wik, Wsv, Wiv};
      src = s6[w] + (size_t)m * 768 * 384;
      dst = wb + (size_t)w * WSZ + (size_t)m * 384 * 768;
      cols = 384;
    } else {
      int u2 = bid - 3456;
      int z = u2 / 576, rem = u2 % 576;
      cx = rem % 24; cy = rem / 24;
      src = (z == 0) ? Wkp : Wvp;
      dst = wb + (size_t)(6 + z) * WSZ;
      cols = 768;
    }
    __shared__ float tile[32][33];
    int d0 = cy * 32, c0 = cx * 32;
    int tx = threadIdx.x & 31, ty = threadIdx.x >> 5;
    #pragma unroll
    for (int i = 0; i < 32; i += 8)
      tile[ty+i][tx] = src[(size_t)(d0+ty+i)*cols + c0 + tx];
    __syncthreads();
    #pragma unroll
    for (int i = 0; i < 32; i += 8)
      dst[(size_t)(c0+ty+i)*768 + d0 + tx] = (h16)tile[tx][ty+i];
    return;
  }
  int row = bid - 4608;
  int b = row >> 9, l = row & 511;
  bool pad = (l < 384) ? (l >= tlen[b]) : ((l-384) >= ilen[b]);
  if (pad) return;
  const float* src = (l < 384) ? (text + ((size_t)b*384 + l)*768)
                               : (images + ((size_t)b*128 + (l-384))*768);
  int t = threadIdx.x;
  float x0 = src[t], x1 = src[t+256], x2 = src[t+512];
  __shared__ float red[8];
  float s = x0 + x1 + x2;
  #pragma unroll
  for (int m = 32; m; m >>= 1) s += __shfl_xor(s, m);
  int wid = t >> 6;
  if ((t & 63) == 0) red[wid] = s;
  __syncthreads();
  float mu = (red[0]+red[1]+red[2]+red[3]) * (1.0f/768.0f);
  float d0 = x0-mu, d1 = x1-mu, d2 = x2-mu;
  float v = d0*d0 + d1*d1 + d2*d2;
  #pragma unroll
  for (int m = 32; m; m >>= 1) v += __shfl_xor(v, m);
  if ((t & 63) == 0) red[4+wid] = v;
  __syncthreads();
  float var = (red[4]+red[5]+red[6]+red[7]) * (1.0f/768.0f);
  float rstd = rsqrtf(var + 1e-5f);
  h16* dst = xn + (size_t)row * 768;
  dst[t]     = (h16)(d0*rstd*g[t]     + be[t]);
  dst[t+256] = (h16)(d1*rstd*g[t+256] + be[t+256]);
  dst[t+512] = (h16)(d2*rstd*g[t+512] + be[t+512]);
}

#define HOFF ((size_t)64*512*384)

// ---------------- GEMM: 128x128, dbuf global_load_lds, XOR-swizzled LDS,
// 2D-grouped XCD mapping (L2 working set < 4MB), LDS-bounce epilogue,
// nontemporal tiled stores.
template<int AMODE>
__global__ __launch_bounds__(256) void k_gemmf2(
    const h16* __restrict__ Asrc, const h16* __restrict__ wb,
    const float* __restrict__ bsq, const float* __restrict__ biq,
    const float* __restrict__ bsk, const float* __restrict__ bik,
    const float* __restrict__ bsv, const float* __restrict__ biv,
    const float* __restrict__ bkp, const float* __restrict__ bvp,
    h16* __restrict__ O0, h16* __restrict__ O1, h16* __restrict__ O2,
    const int* __restrict__ tlen, const int* __restrict__ ilen)
{
  constexpr int NT = (AMODE == 0) ? 18 : 12;
  __shared__ __align__(16) h16 SM[32768];      // 64KB: As[2]@0, Bs[2]@16384(h16)
  h16* As0 = SM;
  h16* Bs0 = SM + 16384;
  const size_t WSZ = 589824;
  int bid = blockIdx.x;
  int xcd = bid & 7, slot = bid >> 3;
  // 2D-grouped (8 mt x 6 nt) within XCD: resident L2 working set ~2.7MB
  constexpr int GM = 8, GN = 6, NGN = NT / GN;
  int g = slot / (GM*GN), r = slot % (GM*GN);
  int mtl = (g / NGN)*GM + r/GN;
  int nt  = (g % NGN)*GN + r%GN;
  int mt = xcd * 32 + mtl;
  int m0 = mt << 7;
  int b = m0 >> 9, l0 = m0 & 511;
  int TL = tlen[b], IL = ilen[b];
  bool skiptile = (l0 < 384) && (TL <= l0);
  int gc0 = nt << 7;
  int widx = gc0 / 768;
  int ncol0 = gc0 % 768;
  bool isimg = (l0 >= 384);

  const h16* BT;
  const float* bias;
  if constexpr (AMODE == 0) {
    BT = wb + ((size_t)(2*widx) + (isimg ? 1 : 0)) * WSZ;
    const float* bt6[6] = {bsq, biq, bsk, bik, bsv, biv};
    bias = bt6[2*widx + (isimg ? 1 : 0)];
  } else {
    BT = wb + (size_t)(6 + widx) * WSZ;
    bias = widx ? bvp : bkp;
  }

  int t = threadIdx.x;
  int lane = t & 63, wid = t >> 6;
  int wm = wid >> 1, wn = wid & 1;
  int lg = lane >> 4, li = lane & 15;

  f32x4 acc44[4][4] = {};

  if (!skiptile) {
    const h16* pA[4]; const h16* pB[4];
    h16* dA[4]; h16* dB[4];
    #pragma unroll
    for (int h = 0; h < 4; ++h) {
      int ci = h*256 + t;
      int row = ci >> 3;
      int cs = (ci & 7) ^ (row & 7);
      if constexpr (AMODE == 0)
        pA[h] = Asrc + (size_t)(m0 + row)*768 + cs*8;
      else
        pA[h] = Asrc + ((size_t)b*512 + l0 + row)*384 + cs*8;
      pB[h] = BT + (size_t)(ncol0 + row)*768 + cs*8;
      dA[h] = &As0[(h*256 + wid*64)*8];
      dB[h] = &Bs0[(h*256 + wid*64)*8];
    }
    const char* baA = (const char*)As0 + (wm*64 + li)*128;
    const char* baB = (const char*)Bs0 + (wn*64 + li)*128;
    int x0 = (lg ^ (li & 7)) << 4;

    #pragma unroll
    for (int h = 0; h < 4; ++h) {
      gld16(dA[h], pA[h]);
      gld16(dB[h], pB[h]);
    }
    __syncthreads();

    #pragma unroll
    for (int kk = 0; kk < 12; ++kk) {
      const int cur = kk & 1;
      if (kk < 11) {
        int ktE = (kk + 1) * 64;
        size_t aoff = (size_t)ktE;
        if constexpr (AMODE == 2) { if (ktE >= 384) aoff += HOFF - 384; }
        #pragma unroll
        for (int h = 0; h < 4; ++h) {
          gld16(dA[h] + (cur^1)*8192, pA[h] + aoff);
          gld16(dB[h] + (cur^1)*8192, pB[h] + ktE);
        }
      }
      const char* cA = baA + cur*16384;
      const char* cB = baB + cur*16384;
      #pragma unroll
      for (int ks = 0; ks < 2; ++ks) {
        int xo = x0 ^ (ks << 6);
        h16x8 af[4], bf[4];
        #pragma unroll
        for (int i = 0; i < 4; ++i) {
          af[i] = *(const h16x8*)(cA + i*2048 + xo);
          bf[i] = *(const h16x8*)(cB + i*2048 + xo);
        }
        #pragma unroll
        for (int i = 0; i < 4; ++i)
          #pragma unroll
          for (int j = 0; j < 4; ++j)
            acc44[i][j] = MFMA(af[i], bf[j], acc44[i][j]);
      }
      __syncthreads();
    }
  }

  // -------- epilogue: bias + pad-zero into LDS tile, barrier, coalesced nt store
  constexpr int PITCH = 136;
  bool vroute = (AMODE == 0) ? (widx == 2) : (widx == 1);
  h16* dout = vroute ? ((AMODE == 0) ? O2 : O1)
                     : ((AMODE == 0) ? (widx == 0 ? O0 : O1) : O0);
  #pragma unroll
  for (int i = 0; i < 4; ++i)
    #pragma unroll
    for (int j = 0; j < 4; ++j) {
      int rowL = wm*64 + i*16 + lg*4;
      int colL = wn*64 + j*16 + li;
      float bv = bias[ncol0 + colL];
      #pragma unroll
      for (int r = 0; r < 4; ++r) {
        int l = l0 + rowL + r;
        float v = acc44[i][j][r] + bv;
        bool pad = (l < 384) ? (l >= TL) : ((l-384) >= IL);
        if (pad) v = 0.0f;
        if (vroute) SM[colL*PITCH + rowL + r] = (h16)v;   // [vcolRel][lRel]
        else        SM[(rowL + r)*PITCH + colL] = (h16)v; // [lRel][colRel]
      }
    }
  __syncthreads();
  int hh = (AMODE == 0 && ncol0 >= 384) ? 1 : 0;  // tile-uniform (128 | 384)
  int kkb = ncol0 - hh*384;
  #pragma unroll
  for (int q = 0; q < 8; ++q) {
    int row = q*16 + (t >> 4);
    int c0 = (t & 15) * 8;
    h16x8 val = *(const h16x8*)&SM[row*PITCH + c0];
    size_t oi;
    if (vroute) {
      int l = l0 + c0;
      int kt = l >> 5, k32 = l & 31;
      if constexpr (AMODE == 0)
        oi = (size_t)(hh*64 + b)*196608 + (size_t)kt*12288 + (size_t)(kkb + row)*32 + k32;
      else
        oi = (size_t)b*393216 + (size_t)kt*24576 + (size_t)(ncol0 + row)*32 + k32;
    } else {
      int l = l0 + row;
      if constexpr (AMODE == 0) {
        int kk = kkb + c0;
        oi = (size_t)(hh*64 + b)*196608 + (size_t)(kk >> 5)*16384 + (size_t)l*32 + (kk & 31);
      } else {
        int col = ncol0 + c0;
        oi = (size_t)b*393216 + (size_t)(col >> 5)*16384 + (size_t)l*32 + (col & 31);
      }
    }
    ntst16(&dout[oi], &val);
  }
}

// ---------------- attention stage 1: 32 q-rows, XCD-pinned, TILED loads,
// setprio around MFMA, LDS-bounced coalesced album store.
__global__ __launch_bounds__(256) void k_attn1(
    const h16* __restrict__ Qt, const h16* __restrict__ Kt,
    const h16* __restrict__ Vt, h16* __restrict__ album,
    const int* __restrict__ tlen, const int* __restrict__ ilen)
{
  __shared__ __align__(16) float S[32*516];
  __shared__ float rowscale[32];
  int bid = blockIdx.x;
  int xcd = bid & 7, slot = bid >> 3;
  int hb = (slot >> 4) * 8 + xcd;
  int q0 = (slot & 15) * 32;
  int b = hb & 63;
  int TL = tlen[b], IL = ilen[b];
  const h16* Qp = Qt + (size_t)hb * 196608;
  const h16* Kp = Kt + (size_t)hb * 196608;
  const h16* Vp = Vt + (size_t)hb * 196608;
  h16* Ap = album + (size_t)hb * 196608;   // row-major [l][384]
  int t = threadIdx.x, lane = t & 63, w = t >> 6;
  int lg = lane >> 4, li = lane & 15;

  bool qskip = (q0 < 384) ? (TL <= q0) : (IL <= q0 - 384);
  if (qskip) {
    h16x8 z = {};
    for (int c = t; c < 1536; c += 256) {
      int row = c / 48, v8 = (c % 48) * 8;
      ntst16(&Ap[(size_t)(q0+row)*384 + v8], &z);
    }
    return;
  }

  h16x8 aq[2][12];
  #pragma unroll
  for (int m = 0; m < 2; ++m)
    #pragma unroll
    for (int ks = 0; ks < 12; ++ks)
      aq[m][ks] = *(const h16x8*)&Qp[(size_t)ks*16384 + (q0 + m*16 + li)*32 + lg*8];

  int kbase = w * 128;
  int LIMw = (w < 3) ? TL : (384 + IL);
  int nvf = (LIMw - kbase + 15) >> 4;
  nvf = nvf < 0 ? 0 : (nvf > 8 ? 8 : nvf);
  for (int nf = 0; nf < nvf; ++nf) {
    int kcol = kbase + nf*16;
    f32x4 acc0 = {0,0,0,0}, acc1 = {0,0,0,0};
    __builtin_amdgcn_s_setprio(1);
    #pragma unroll
    for (int ks = 0; ks < 12; ++ks) {
      h16x8 bk = *(const h16x8*)&Kp[(size_t)ks*16384 + (kcol + li)*32 + lg*8];
      acc0 = MFMA(aq[0][ks], bk, acc0);
      acc1 = MFMA(aq[1][ks], bk, acc1);
    }
    __builtin_amdgcn_s_setprio(0);
    #pragma unroll
    for (int r = 0; r < 4; ++r) {
      int c = kcol + li;
      int row0 = lg*4 + r;
      float v0 = acc0[r];
      if (v0 == 0.0f || (q0 + row0) == c) v0 = -__builtin_inff();
      S[row0*516 + c] = v0;
      int row1 = 16 + lg*4 + r;
      float v1 = acc1[r];
      if (v1 == 0.0f || (q0 + row1) == c) v1 = -__builtin_inff();
      S[row1*516 + c] = v1;
    }
  }
  for (int nf = nvf; nf < 8; ++nf) {
    int c = kbase + nf*16 + li;
    #pragma unroll
    for (int r = 0; r < 4; ++r) {
      S[(lg*4 + r)*516 + c] = -__builtin_inff();
      S[(16 + lg*4 + r)*516 + c] = -__builtin_inff();
    }
  }
  __syncthreads();
  {
    int row = t >> 3, ci = t & 7;
    float* Sr = &S[row*516];
    f32x4 mx4 = {-3e38f, -3e38f, -3e38f, -3e38f};
    #pragma unroll
    for (int j = 0; j < 16; ++j) {
      f32x4 v = *(const f32x4*)&Sr[ci*4 + j*32];
      #pragma unroll
      for (int k = 0; k < 4; ++k) mx4[k] = fmaxf(mx4[k], v[k]);
    }
    float mx = fmaxf(fmaxf(mx4[0], mx4[1]), fmaxf(mx4[2], mx4[3]));
    mx = fmaxf(mx, __shfl_xor(mx, 1));
    mx = fmaxf(mx, __shfl_xor(mx, 2));
    mx = fmaxf(mx, __shfl_xor(mx, 4));
    float sum = 0.0f;
    #pragma unroll
    for (int j = 0; j < 16; ++j) {
      f32x4 v = *(const f32x4*)&Sr[ci*4 + j*32];
      f32x4 e;
      #pragma unroll
      for (int k = 0; k < 4; ++k) e[k] = __expf(v[k] - mx);
      *(f32x4*)&Sr[ci*4 + j*32] = e;
      sum += e[0] + e[1] + e[2] + e[3];
    }
    sum += __shfl_xor(sum, 1);
    sum += __shfl_xor(sum, 2);
    sum += __shfl_xor(sum, 4);
    if (ci == 0) rowscale[row] = 1.0f / (sum > 0.0f ? sum : 1.0f);
  }
  __syncthreads();
  f32x4 oacc[2][6] = {};
  int v0w = w * 96;
  auto pv = [&](int kt) {
    int k0 = kt * 32;
    h16x8 bv[6];
    #pragma unroll
    for (int n = 0; n < 6; ++n)
      bv[n] = *(const h16x8*)&Vp[(size_t)kt*12288 + (v0w + n*16 + li)*32 + lg*8];
    #pragma unroll
    for (int m = 0; m < 2; ++m) {
      int row = m*16 + li;
      f32x4 p0 = *(const f32x4*)&S[row*516 + k0 + lg*8];
      f32x4 p1 = *(const f32x4*)&S[row*516 + k0 + lg*8 + 4];
      h16x8 pa;
      pa[0]=(h16)p0[0]; pa[1]=(h16)p0[1]; pa[2]=(h16)p0[2]; pa[3]=(h16)p0[3];
      pa[4]=(h16)p1[0]; pa[5]=(h16)p1[1]; pa[6]=(h16)p1[2]; pa[7]=(h16)p1[3];
      __builtin_amdgcn_s_setprio(1);
      #pragma unroll
      for (int n = 0; n < 6; ++n)
        oacc[m][n] = MFMA(pa, bv[n], oacc[m][n]);
      __builtin_amdgcn_s_setprio(0);
    }
  };
  int n1 = (TL + 31) >> 5; n1 = n1 > 12 ? 12 : n1;
  int n2 = (IL + 31) >> 5; n2 = n2 > 4 ? 4 : n2;
  for (int kt = 0; kt < n1; ++kt) pv(kt);
  for (int kt = 12; kt < 12 + n2; ++kt) pv(kt);
  // bounce output through LDS (reuse S) for coalesced nt stores
  __syncthreads();
  h16* S16 = (h16*)S;
  #pragma unroll
  for (int m = 0; m < 2; ++m)
    #pragma unroll
    for (int n = 0; n < 6; ++n)
      #pragma unroll
      for (int r = 0; r < 4; ++r) {
        int row = m*16 + lg*4 + r;
        int col = v0w + n*16 + li;
        S16[row*392 + col] = (h16)(oacc[m][n][r] * rowscale[row]);
      }
  __syncthreads();
  for (int c = t; c < 1536; c += 256) {
    int row = c / 48, v8 = (c % 48) * 8;
    h16x8 val = *(const h16x8*)&S16[row*392 + v8];
    ntst16(&Ap[(size_t)(q0+row)*384 + v8], &val);
  }
}

// ---------------- attention stage 2 + mean: one block per (b, vh), TILED loads
__global__ __launch_bounds__(256) void k_attn2(
    const float* __restrict__ query, const h16* __restrict__ keysT,
    const h16* __restrict__ valsT, const int* __restrict__ qlen,
    const int* __restrict__ tlen, const int* __restrict__ ilen,
    float* __restrict__ out)
{
  __shared__ __align__(16) float S[32*516];
  __shared__ __align__(16) h16 UB[32*776];
  __shared__ float rowscale[32];
  int bid = blockIdx.x;
  int b = bid >> 1, vh = bid & 1;
  const float* Qp = query + (size_t)b*24*768;
  const h16* Kp = keysT + (size_t)b*393216;
  const h16* Vp = valsT + (size_t)b*393216;
  int t = threadIdx.x, lane = t & 63, w = t >> 6;
  int lg = lane >> 4, li = lane & 15;
  int ql = qlen[b];
  int TL = tlen[b], IL = ilen[b];
  for (int c = t; c < 3072; c += 256) {
    int row = c / 96, vv = (c % 96) * 8;
    h16x8 a = {};
    if (row < 24 && row < ql) {
      f32x4 f0 = *(const f32x4*)&Qp[(size_t)row*768 + vv];
      f32x4 f1 = *(const f32x4*)&Qp[(size_t)row*768 + vv + 4];
      a[0]=(h16)f0[0]; a[1]=(h16)f0[1]; a[2]=(h16)f0[2]; a[3]=(h16)f0[3];
      a[4]=(h16)f1[0]; a[5]=(h16)f1[1]; a[6]=(h16)f1[2]; a[7]=(h16)f1[3];
    }
    *(h16x8*)&UB[row*776 + vv] = a;
  }
  __syncthreads();
  int kbase = w * 128;
  int LIMw = (w < 3) ? TL : (384 + IL);
  int nvf = (LIMw - kbase + 15) >> 4;
  nvf = nvf < 0 ? 0 : (nvf > 8 ? 8 : nvf);
  for (int nf = 0; nf < nvf; ++nf) {
    int kcol = kbase + nf*16;
    f32x4 acc0 = {0,0,0,0}, acc1 = {0,0,0,0};
    #pragma unroll
    for (int ks = 0; ks < 24; ++ks) {
      h16x8 a0 = *(const h16x8*)&UB[(li)*776      + ks*32 + lg*8];
      h16x8 a1 = *(const h16x8*)&UB[(16 + li)*776 + ks*32 + lg*8];
      h16x8 bk = *(const h16x8*)&Kp[(size_t)ks*16384 + (kcol + li)*32 + lg*8];
      acc0 = MFMA(a0, bk, acc0);
      acc1 = MFMA(a1, bk, acc1);
    }
    #pragma unroll
    for (int r = 0; r < 4; ++r) {
      int c = kcol + li;
      float v0 = acc0[r];
      if (v0 == 0.0f) v0 = -__builtin_inff();
      S[(lg*4 + r)*516 + c] = v0;
      float v1 = acc1[r];
      if (v1 == 0.0f) v1 = -__builtin_inff();
      S[(16 + lg*4 + r)*516 + c] = v1;
    }
  }
  for (int nf = nvf; nf < 8; ++nf) {
    int c = kbase + nf*16 + li;
    #pragma unroll
    for (int r = 0; r < 4; ++r) {
      S[(lg*4 + r)*516 + c] = -__builtin_inff();
      S[(16 + lg*4 + r)*516 + c] = -__builtin_inff();
    }
  }
  __syncthreads();
  {
    int row = t >> 3, ci = t & 7;
    float* Sr = &S[row*516];
    f32x4 mx4 = {-3e38f, -3e38f, -3e38f, -3e38f};
    #pragma unroll
    for (int j = 0; j < 16; ++j) {
      f32x4 v = *(const f32x4*)&Sr[ci*4 + j*32];
      #pragma unroll
      for (int k = 0; k < 4; ++k) mx4[k] = fmaxf(mx4[k], v[k]);
    }
    float mx = fmaxf(fmaxf(mx4[0], mx4[1]), fmaxf(mx4[2], mx4[3]));
    mx = fmaxf(mx, __shfl_xor(mx, 1));
    mx = fmaxf(mx, __shfl_xor(mx, 2));
    mx = fmaxf(mx, __shfl_xor(mx, 4));
    float sum = 0.0f;
    #pragma unroll
    for (int j = 0; j < 16; ++j) {
      f32x4 v = *(const f32x4*)&Sr[ci*4 + j*32];
      f32x4 e;
      #pragma unroll
      for (int k = 0; k < 4; ++k) e[k] = __expf(v[k] - mx);
      *(f32x4*)&Sr[ci*4 + j*32] = e;
      sum += e[0] + e[1] + e[2] + e[3];
    }
    sum += __shfl_xor(sum, 1);
    sum += __shfl_xor(sum, 2);
    sum += __shfl_xor(sum, 4);
    if (ci == 0) rowscale[row] = 1.0f / (sum > 0.0f ? sum : 1.0f);
  }
  __syncthreads();
  int n1 = (TL + 31) >> 5; n1 = n1 > 12 ? 12 : n1;
  int n2 = (IL + 31) >> 5; n2 = n2 > 4 ? 4 : n2;
  {
    f32x4 oacc[2][6] = {};
    auto pv = [&](int kt) {
      int k0 = kt * 32;
      h16x8 bv[6];
      #pragma unroll
      for (int n = 0; n < 6; ++n)
        bv[n] = *(const h16x8*)&Vp[(size_t)kt*24576 + (vh*384 + w*96 + n*16 + li)*32 + lg*8];
      #pragma unroll
      for (int m = 0; m < 2; ++m) {
        int row = m*16 + li;
        f32x4 p0 = *(const f32x4*)&S[row*516 + k0 + lg*8];
        f32x4 p1 = *(const f32x4*)&S[row*516 + k0 + lg*8 + 4];
        h16x8 pa;
        pa[0]=(h16)p0[0]; pa[1]=(h16)p0[1]; pa[2]=(h16)p0[2]; pa[3]=(h16)p0[3];
        pa[4]=(h16)p1[0]; pa[5]=(h16)p1[1]; pa[6]=(h16)p1[2]; pa[7]=(h16)p1[3];
        #pragma unroll
        for (int n = 0; n < 6; ++n)
          oacc[m][n] = MFMA(pa, bv[n], oacc[m][n]);
      }
    };
    for (int kt = 0; kt < n1; ++kt) pv(kt);
    for (int kt = 12; kt < 12 + n2; ++kt) pv(kt);
    #pragma unroll
    for (int n = 0; n < 6; ++n) {
      float cs = 0.0f;
      #pragma unroll
      for (int m = 0; m < 2; ++m)
        #pragma unroll
        for (int r = 0; r < 4; ++r)
          cs += oacc[m][n][r] * rowscale[m*16 + lg*4 + r];
      cs += __shfl_xor(cs, 16);
      cs += __shfl_xor(cs, 32);
      if (lg == 0) out[(size_t)b*768 + vh*384 + w*96 + n*16 + li] = cs * (1.0f/24.0f);
    }
  }
}

extern "C" void kernel_launch(void* const* d_in, const int* in_sizes, int n_in,
                              void* d_out, int out_size, void* d_ws, size_t ws_size,
                              hipStream_t stream)
{
  (void)in_sizes; (void)n_in;
  const float* text  = (const float*)d_in[0];
  const float* images= (const float*)d_in[1];
  const float* query = (const float*)d_in[2];
  const float* ln_g  = (const float*)d_in[3];
  const float* ln_b  = (const float*)d_in[4];
  const float* Wsq = (const float*)d_in[5];
  const float* bsq = (const float*)d_in[6];
  const float* Wiq = (const float*)d_in[7];
  const float* biq = (const float*)d_in[8];
  const float* Wsk = (const float*)d_in[9];
  const float* bsk = (const float*)d_in[10];
  const float* Wik = (const float*)d_in[11];
  const float* bik = (const float*)d_in[12];
  const float* Wsv = (const float*)d_in[13];
  const float* bsv = (const float*)d_in[14];
  const float* Wiv = (const float*)d_in[15];
  const float* biv = (const float*)d_in[16];
  const float* Wkp = (const float*)d_in[17];
  const float* bkp = (const float*)d_in[18];
  const float* Wvp = (const float*)d_in[19];
  const float* bvp = (const float*)d_in[20];
  const int* tlen = (const int*)d_in[21];
  const int* ilen = (const int*)d_in[22];
  const int* qlen = (const int*)d_in[23];

  const size_t NEED = 160694272 + 50331648;   // 211,025,920
  if (ws_size < NEED) {
    k_diag<<<dim3((out_size+255)/256), dim3(256), 0, stream>>>((float*)d_out, out_size, 1.0e6f);
    return;
  }
  h16* wb = (h16*)((char*)d_ws + 262144);
  const size_t WSZ = 589824;
  const size_t TSZ = (size_t)32768*768;
  h16* Qb = wb + 8*WSZ;
  h16* Kb = Qb + TSZ;
  h16* Vb = Kb + TSZ;
  h16* XNb = (h16*)((char*)d_ws + 160694272);

  dim3 blk(256);

  k_prep<<<dim3(4608 + 32768), blk, 0, stream>>>(
      Wsq, Wiq, Wsk, Wik, Wsv, Wiv, Wkp, Wvp, wb,
      text, images, ln_g, ln_b, XNb, tlen, ilen);

  k_gemmf2<0><<<dim3(4608), blk, 0, stream>>>(XNb, wb,
      bsq, biq, bsk, bik, bsv, biv, bkp, bvp, Qb, Kb, Vb, tlen, ilen);

  k_attn1<<<dim3(2048), blk, 0, stream>>>(Qb, Kb, Vb, XNb, tlen, ilen);

  k_gemmf2<2><<<dim3(3072), blk, 0, stream>>>(XNb, wb,
      bsq, biq, bsk, bik, bsv, biv, bkp, bvp, Kb, Vb, nullptr, tlen, ilen);

  k_attn2<<<dim3(128), blk, 0, stream>>>(query, Kb, Vb, qlen, tlen, ilen, (float*)d_out);
}

// Round 17
// 378.667 us; speedup vs baseline: 1.1513x; 1.1513x over previous
//
#include <hip/hip_runtime.h>
#include <hip/hip_bf16.h>

typedef _Float16 h16;
typedef _Float16 h16x8 __attribute__((ext_vector_type(8)));
typedef _Float16 h16x4 __attribute__((ext_vector_type(4)));
typedef float    f32x4 __attribute__((ext_vector_type(4)));
typedef unsigned int u32x4 __attribute__((ext_vector_type(4)));

#define MFMA(a,b,c) __builtin_amdgcn_mfma_f32_16x16x32_f16((a),(b),(c),0,0,0)

// H=2 B=64 LT=384 LI=128 L=512 D=768 K=V=384 DK=DV=768 LQ=24
// Tiled layouts (MFMA-native):
//  Q,K:  [hb][ks=12][row=512][d32]; V: [hb][kt=16][vcol=384][k32]
//  keys: [b][ks=24][key=512][d32];  vals: [b][kt=16][vcol=768][k32]

typedef __attribute__((address_space(1))) const void gas_void;
typedef __attribute__((address_space(3))) void las_void;
__device__ __forceinline__ void gld16(void* l, const void* g) {
  __builtin_amdgcn_global_load_lds((gas_void*)g, (las_void*)l, 16, 0, 0);
}

__global__ __launch_bounds__(256) void k_diag(float* out, int n, float val) {
  int i = blockIdx.x * 256 + threadIdx.x;
  if (i < n) out[i] = val;
}

// ---------------- FUSED prep: weight transposes (bid<4608) + LayerNorm (rest)
__global__ __launch_bounds__(256) void k_prep(
    const float* __restrict__ Wsq, const float* __restrict__ Wiq,
    const float* __restrict__ Wsk, const float* __restrict__ Wik,
    const float* __restrict__ Wsv, const float* __restrict__ Wiv,
    const float* __restrict__ Wkp, const float* __restrict__ Wvp,
    h16* __restrict__ wb,
    const float* __restrict__ text, const float* __restrict__ images,
    const float* __restrict__ g, const float* __restrict__ be,
    h16* __restrict__ xn,
    const int* __restrict__ tlen, const int* __restrict__ ilen)
{
  const size_t WSZ = 589824;
  int bid = blockIdx.x;
  if (bid < 4608) {
    const float* src; h16* dst;
    int cols, cx, cy;
    if (bid < 3456) {
      int z = bid / 288, rem = bid % 288;
      cx = rem % 12; cy = rem / 12;
      int w = z >> 1, m = z & 1;
      const float* s6[6] = {Wsq, Wiq, Wsk, Wik, Wsv, Wiv};
      src = s6[w] + (size_t)m * 768 * 384;
      dst = wb + (size_t)w * WSZ + (size_t)m * 384 * 768;
      cols = 384;
    } else {
      int u2 = bid - 3456;
      int z = u2 / 576, rem = u2 % 576;
      cx = rem % 24; cy = rem / 24;
      src = (z == 0) ? Wkp : Wvp;
      dst = wb + (size_t)(6 + z) * WSZ;
      cols = 768;
    }
    __shared__ float tile[32][33];
    int d0 = cy * 32, c0 = cx * 32;
    int tx = threadIdx.x & 31, ty = threadIdx.x >> 5;
    #pragma unroll
    for (int i = 0; i < 32; i += 8)
      tile[ty+i][tx] = src[(size_t)(d0+ty+i)*cols + c0 + tx];
    __syncthreads();
    #pragma unroll
    for (int i = 0; i < 32; i += 8)
      dst[(size_t)(c0+ty+i)*768 + d0 + tx] = (h16)tile[tx][ty+i];
    return;
  }
  int row = bid - 4608;
  int b = row >> 9, l = row & 511;
  bool pad = (l < 384) ? (l >= tlen[b]) : ((l-384) >= ilen[b]);
  if (pad) return;
  const float* src = (l < 384) ? (text + ((size_t)b*384 + l)*768)
                               : (images + ((size_t)b*128 + (l-384))*768);
  int t = threadIdx.x;
  float x0 = src[t], x1 = src[t+256], x2 = src[t+512];
  __shared__ float red[8];
  float s = x0 + x1 + x2;
  #pragma unroll
  for (int m = 32; m; m >>= 1) s += __shfl_xor(s, m);
  int wid = t >> 6;
  if ((t & 63) == 0) red[wid] = s;
  __syncthreads();
  float mu = (red[0]+red[1]+red[2]+red[3]) * (1.0f/768.0f);
  float d0 = x0-mu, d1 = x1-mu, d2 = x2-mu;
  float v = d0*d0 + d1*d1 + d2*d2;
  #pragma unroll
  for (int m = 32; m; m >>= 1) v += __shfl_xor(v, m);
  if ((t & 63) == 0) red[4+wid] = v;
  __syncthreads();
  float var = (red[4]+red[5]+red[6]+red[7]) * (1.0f/768.0f);
  float rstd = rsqrtf(var + 1e-5f);
  h16* dst = xn + (size_t)row * 768;
  dst[t]     = (h16)(d0*rstd*g[t]     + be[t]);
  dst[t+256] = (h16)(d1*rstd*g[t+256] + be[t+256]);
  dst[t+512] = (h16)(d2*rstd*g[t+512] + be[t+512]);
}

#define HOFF ((size_t)64*512*384)

// ---------------- GEMM: 128x128, dbuf global_load_lds, XOR-swizzled LDS,
// 2D-grouped XCD mapping (L2 working set < 4MB), LDS-bounce epilogue,
// regular tiled stores (intermediates are re-read: keep them cached).
template<int AMODE>
__global__ __launch_bounds__(256) void k_gemmf2(
    const h16* __restrict__ Asrc, const h16* __restrict__ wb,
    const float* __restrict__ bsq, const float* __restrict__ biq,
    const float* __restrict__ bsk, const float* __restrict__ bik,
    const float* __restrict__ bsv, const float* __restrict__ biv,
    const float* __restrict__ bkp, const float* __restrict__ bvp,
    h16* __restrict__ O0, h16* __restrict__ O1, h16* __restrict__ O2,
    const int* __restrict__ tlen, const int* __restrict__ ilen)
{
  constexpr int NT = (AMODE == 0) ? 18 : 12;
  __shared__ __align__(16) h16 SM[32768];      // 64KB: As[2]@0, Bs[2]@16384(h16)
  h16* As0 = SM;
  h16* Bs0 = SM + 16384;
  const size_t WSZ = 589824;
  int bid = blockIdx.x;
  int xcd = bid & 7, slot = bid >> 3;
  // 2D-grouped (8 mt x 6 nt) within XCD: resident L2 working set ~2.7MB
  constexpr int GM = 8, GN = 6, NGN = NT / GN;
  int g = slot / (GM*GN), r = slot % (GM*GN);
  int mtl = (g / NGN)*GM + r/GN;
  int nt  = (g % NGN)*GN + r%GN;
  int mt = xcd * 32 + mtl;
  int m0 = mt << 7;
  int b = m0 >> 9, l0 = m0 & 511;
  int TL = tlen[b], IL = ilen[b];
  bool skiptile = (l0 < 384) && (TL <= l0);
  int gc0 = nt << 7;
  int widx = gc0 / 768;
  int ncol0 = gc0 % 768;
  bool isimg = (l0 >= 384);

  const h16* BT;
  const float* bias;
  if constexpr (AMODE == 0) {
    BT = wb + ((size_t)(2*widx) + (isimg ? 1 : 0)) * WSZ;
    const float* bt6[6] = {bsq, biq, bsk, bik, bsv, biv};
    bias = bt6[2*widx + (isimg ? 1 : 0)];
  } else {
    BT = wb + (size_t)(6 + widx) * WSZ;
    bias = widx ? bvp : bkp;
  }

  int t = threadIdx.x;
  int lane = t & 63, wid = t >> 6;
  int wm = wid >> 1, wn = wid & 1;
  int lg = lane >> 4, li = lane & 15;

  f32x4 acc44[4][4] = {};

  if (!skiptile) {
    const h16* pA[4]; const h16* pB[4];
    h16* dA[4]; h16* dB[4];
    #pragma unroll
    for (int h = 0; h < 4; ++h) {
      int ci = h*256 + t;
      int row = ci >> 3;
      int cs = (ci & 7) ^ (row & 7);
      if constexpr (AMODE == 0)
        pA[h] = Asrc + (size_t)(m0 + row)*768 + cs*8;
      else
        pA[h] = Asrc + ((size_t)b*512 + l0 + row)*384 + cs*8;
      pB[h] = BT + (size_t)(ncol0 + row)*768 + cs*8;
      dA[h] = &As0[(h*256 + wid*64)*8];
      dB[h] = &Bs0[(h*256 + wid*64)*8];
    }
    const char* baA = (const char*)As0 + (wm*64 + li)*128;
    const char* baB = (const char*)Bs0 + (wn*64 + li)*128;
    int x0 = (lg ^ (li & 7)) << 4;

    #pragma unroll
    for (int h = 0; h < 4; ++h) {
      gld16(dA[h], pA[h]);
      gld16(dB[h], pB[h]);
    }
    __syncthreads();

    #pragma unroll
    for (int kk = 0; kk < 12; ++kk) {
      const int cur = kk & 1;
      if (kk < 11) {
        int ktE = (kk + 1) * 64;
        size_t aoff = (size_t)ktE;
        if constexpr (AMODE == 2) { if (ktE >= 384) aoff += HOFF - 384; }
        #pragma unroll
        for (int h = 0; h < 4; ++h) {
          gld16(dA[h] + (cur^1)*8192, pA[h] + aoff);
          gld16(dB[h] + (cur^1)*8192, pB[h] + ktE);
        }
      }
      const char* cA = baA + cur*16384;
      const char* cB = baB + cur*16384;
      #pragma unroll
      for (int ks = 0; ks < 2; ++ks) {
        int xo = x0 ^ (ks << 6);
        h16x8 af[4], bf[4];
        #pragma unroll
        for (int i = 0; i < 4; ++i) {
          af[i] = *(const h16x8*)(cA + i*2048 + xo);
          bf[i] = *(const h16x8*)(cB + i*2048 + xo);
        }
        #pragma unroll
        for (int i = 0; i < 4; ++i)
          #pragma unroll
          for (int j = 0; j < 4; ++j)
            acc44[i][j] = MFMA(af[i], bf[j], acc44[i][j]);
      }
      __syncthreads();
    }
  }

  // -------- epilogue: bias + pad-zero into LDS tile, barrier, coalesced store
  constexpr int PITCH = 136;
  bool vroute = (AMODE == 0) ? (widx == 2) : (widx == 1);
  h16* dout = vroute ? ((AMODE == 0) ? O2 : O1)
                     : ((AMODE == 0) ? (widx == 0 ? O0 : O1) : O0);
  #pragma unroll
  for (int i = 0; i < 4; ++i)
    #pragma unroll
    for (int j = 0; j < 4; ++j) {
      int rowL = wm*64 + i*16 + lg*4;
      int colL = wn*64 + j*16 + li;
      float bv = bias[ncol0 + colL];
      #pragma unroll
      for (int r = 0; r < 4; ++r) {
        int l = l0 + rowL + r;
        float v = acc44[i][j][r] + bv;
        bool pad = (l < 384) ? (l >= TL) : ((l-384) >= IL);
        if (pad) v = 0.0f;
        if (vroute) SM[colL*PITCH + rowL + r] = (h16)v;   // [vcolRel][lRel]
        else        SM[(rowL + r)*PITCH + colL] = (h16)v; // [lRel][colRel]
      }
    }
  __syncthreads();
  int hh = (AMODE == 0 && ncol0 >= 384) ? 1 : 0;  // tile-uniform (128 | 384)
  int kkb = ncol0 - hh*384;
  #pragma unroll
  for (int q = 0; q < 8; ++q) {
    int row = q*16 + (t >> 4);
    int c0 = (t & 15) * 8;
    h16x8 val = *(const h16x8*)&SM[row*PITCH + c0];
    size_t oi;
    if (vroute) {
      int l = l0 + c0;
      int kt = l >> 5, k32 = l & 31;
      if constexpr (AMODE == 0)
        oi = (size_t)(hh*64 + b)*196608 + (size_t)kt*12288 + (size_t)(kkb + row)*32 + k32;
      else
        oi = (size_t)b*393216 + (size_t)kt*24576 + (size_t)(ncol0 + row)*32 + k32;
    } else {
      int l = l0 + row;
      if constexpr (AMODE == 0) {
        int kk = kkb + c0;
        oi = (size_t)(hh*64 + b)*196608 + (size_t)(kk >> 5)*16384 + (size_t)l*32 + (kk & 31);
      } else {
        int col = ncol0 + c0;
        oi = (size_t)b*393216 + (size_t)(col >> 5)*16384 + (size_t)l*32 + (col & 31);
      }
    }
    *(u32x4*)&dout[oi] = *(u32x4*)&val;
  }
}

// ---------------- attention stage 1: 32 q-rows, XCD-pinned, TILED loads,
// LDS-bounced coalesced album store (regular stores; no setprio).
__global__ __launch_bounds__(256) void k_attn1(
    const h16* __restrict__ Qt, const h16* __restrict__ Kt,
    const h16* __restrict__ Vt, h16* __restrict__ album,
    const int* __restrict__ tlen, const int* __restrict__ ilen)
{
  __shared__ __align__(16) float S[32*516];
  __shared__ float rowscale[32];
  int bid = blockIdx.x;
  int xcd = bid & 7, slot = bid >> 3;
  int hb = (slot >> 4) * 8 + xcd;
  int q0 = (slot & 15) * 32;
  int b = hb & 63;
  int TL = tlen[b], IL = ilen[b];
  const h16* Qp = Qt + (size_t)hb * 196608;
  const h16* Kp = Kt + (size_t)hb * 196608;
  const h16* Vp = Vt + (size_t)hb * 196608;
  h16* Ap = album + (size_t)hb * 196608;   // row-major [l][384]
  int t = threadIdx.x, lane = t & 63, w = t >> 6;
  int lg = lane >> 4, li = lane & 15;

  bool qskip = (q0 < 384) ? (TL <= q0) : (IL <= q0 - 384);
  if (qskip) {
    h16x8 z = {};
    for (int c = t; c < 1536; c += 256) {
      int row = c / 48, v8 = (c % 48) * 8;
      *(h16x8*)&Ap[(size_t)(q0+row)*384 + v8] = z;
    }
    return;
  }

  h16x8 aq[2][12];
  #pragma unroll
  for (int m = 0; m < 2; ++m)
    #pragma unroll
    for (int ks = 0; ks < 12; ++ks)
      aq[m][ks] = *(const h16x8*)&Qp[(size_t)ks*16384 + (q0 + m*16 + li)*32 + lg*8];

  int kbase = w * 128;
  int LIMw = (w < 3) ? TL : (384 + IL);
  int nvf = (LIMw - kbase + 15) >> 4;
  nvf = nvf < 0 ? 0 : (nvf > 8 ? 8 : nvf);
  for (int nf = 0; nf < nvf; ++nf) {
    int kcol = kbase + nf*16;
    f32x4 acc0 = {0,0,0,0}, acc1 = {0,0,0,0};
    #pragma unroll
    for (int ks = 0; ks < 12; ++ks) {
      h16x8 bk = *(const h16x8*)&Kp[(size_t)ks*16384 + (kcol + li)*32 + lg*8];
      acc0 = MFMA(aq[0][ks], bk, acc0);
      acc1 = MFMA(aq[1][ks], bk, acc1);
    }
    #pragma unroll
    for (int r = 0; r < 4; ++r) {
      int c = kcol + li;
      int row0 = lg*4 + r;
      float v0 = acc0[r];
      if (v0 == 0.0f || (q0 + row0) == c) v0 = -__builtin_inff();
      S[row0*516 + c] = v0;
      int row1 = 16 + lg*4 + r;
      float v1 = acc1[r];
      if (v1 == 0.0f || (q0 + row1) == c) v1 = -__builtin_inff();
      S[row1*516 + c] = v1;
    }
  }
  for (int nf = nvf; nf < 8; ++nf) {
    int c = kbase + nf*16 + li;
    #pragma unroll
    for (int r = 0; r < 4; ++r) {
      S[(lg*4 + r)*516 + c] = -__builtin_inff();
      S[(16 + lg*4 + r)*516 + c] = -__builtin_inff();
    }
  }
  __syncthreads();
  {
    int row = t >> 3, ci = t & 7;
    float* Sr = &S[row*516];
    f32x4 mx4 = {-3e38f, -3e38f, -3e38f, -3e38f};
    #pragma unroll
    for (int j = 0; j < 16; ++j) {
      f32x4 v = *(const f32x4*)&Sr[ci*4 + j*32];
      #pragma unroll
      for (int k = 0; k < 4; ++k) mx4[k] = fmaxf(mx4[k], v[k]);
    }
    float mx = fmaxf(fmaxf(mx4[0], mx4[1]), fmaxf(mx4[2], mx4[3]));
    mx = fmaxf(mx, __shfl_xor(mx, 1));
    mx = fmaxf(mx, __shfl_xor(mx, 2));
    mx = fmaxf(mx, __shfl_xor(mx, 4));
    float sum = 0.0f;
    #pragma unroll
    for (int j = 0; j < 16; ++j) {
      f32x4 v = *(const f32x4*)&Sr[ci*4 + j*32];
      f32x4 e;
      #pragma unroll
      for (int k = 0; k < 4; ++k) e[k] = __expf(v[k] - mx);
      *(f32x4*)&Sr[ci*4 + j*32] = e;
      sum += e[0] + e[1] + e[2] + e[3];
    }
    sum += __shfl_xor(sum, 1);
    sum += __shfl_xor(sum, 2);
    sum += __shfl_xor(sum, 4);
    if (ci == 0) rowscale[row] = 1.0f / (sum > 0.0f ? sum : 1.0f);
  }
  __syncthreads();
  f32x4 oacc[2][6] = {};
  int v0w = w * 96;
  auto pv = [&](int kt) {
    int k0 = kt * 32;
    h16x8 bv[6];
    #pragma unroll
    for (int n = 0; n < 6; ++n)
      bv[n] = *(const h16x8*)&Vp[(size_t)kt*12288 + (v0w + n*16 + li)*32 + lg*8];
    #pragma unroll
    for (int m = 0; m < 2; ++m) {
      int row = m*16 + li;
      f32x4 p0 = *(const f32x4*)&S[row*516 + k0 + lg*8];
      f32x4 p1 = *(const f32x4*)&S[row*516 + k0 + lg*8 + 4];
      h16x8 pa;
      pa[0]=(h16)p0[0]; pa[1]=(h16)p0[1]; pa[2]=(h16)p0[2]; pa[3]=(h16)p0[3];
      pa[4]=(h16)p1[0]; pa[5]=(h16)p1[1]; pa[6]=(h16)p1[2]; pa[7]=(h16)p1[3];
      #pragma unroll
      for (int n = 0; n < 6; ++n)
        oacc[m][n] = MFMA(pa, bv[n], oacc[m][n]);
    }
  };
  int n1 = (TL + 31) >> 5; n1 = n1 > 12 ? 12 : n1;
  int n2 = (IL + 31) >> 5; n2 = n2 > 4 ? 4 : n2;
  for (int kt = 0; kt < n1; ++kt) pv(kt);
  for (int kt = 12; kt < 12 + n2; ++kt) pv(kt);
  // bounce output through LDS (reuse S) for coalesced stores
  __syncthreads();
  h16* S16 = (h16*)S;
  #pragma unroll
  for (int m = 0; m < 2; ++m)
    #pragma unroll
    for (int n = 0; n < 6; ++n)
      #pragma unroll
      for (int r = 0; r < 4; ++r) {
        int row = m*16 + lg*4 + r;
        int col = v0w + n*16 + li;
        S16[row*392 + col] = (h16)(oacc[m][n][r] * rowscale[row]);
      }
  __syncthreads();
  for (int c = t; c < 1536; c += 256) {
    int row = c / 48, v8 = (c % 48) * 8;
    h16x8 val = *(const h16x8*)&S16[row*392 + v8];
    *(u32x4*)&Ap[(size_t)(q0+row)*384 + v8] = *(u32x4*)&val;
  }
}

// ---------------- attention stage 2 + mean: one block per (b, vh), TILED loads
__global__ __launch_bounds__(256) void k_attn2(
    const float* __restrict__ query, const h16* __restrict__ keysT,
    const h16* __restrict__ valsT, const int* __restrict__ qlen,
    const int* __restrict__ tlen, const int* __restrict__ ilen,
    float* __restrict__ out)
{
  __shared__ __align__(16) float S[32*516];
  __shared__ __align__(16) h16 UB[32*776];
  __shared__ float rowscale[32];
  int bid = blockIdx.x;
  int b = bid >> 1, vh = bid & 1;
  const float* Qp = query + (size_t)b*24*768;
  const h16* Kp = keysT + (size_t)b*393216;
  const h16* Vp = valsT + (size_t)b*393216;
  int t = threadIdx.x, lane = t & 63, w = t >> 6;
  int lg = lane >> 4, li = lane & 15;
  int ql = qlen[b];
  int TL = tlen[b], IL = ilen[b];
  for (int c = t; c < 3072; c += 256) {
    int row = c / 96, vv = (c % 96) * 8;
    h16x8 a = {};
    if (row < 24 && row < ql) {
      f32x4 f0 = *(const f32x4*)&Qp[(size_t)row*768 + vv];
      f32x4 f1 = *(const f32x4*)&Qp[(size_t)row*768 + vv + 4];
      a[0]=(h16)f0[0]; a[1]=(h16)f0[1]; a[2]=(h16)f0[2]; a[3]=(h16)f0[3];
      a[4]=(h16)f1[0]; a[5]=(h16)f1[1]; a[6]=(h16)f1[2]; a[7]=(h16)f1[3];
    }
    *(h16x8*)&UB[row*776 + vv] = a;
  }
  __syncthreads();
  int kbase = w * 128;
  int LIMw = (w < 3) ? TL : (384 + IL);
  int nvf = (LIMw - kbase + 15) >> 4;
  nvf = nvf < 0 ? 0 : (nvf > 8 ? 8 : nvf);
  for (int nf = 0; nf < nvf; ++nf) {
    int kcol = kbase + nf*16;
    f32x4 acc0 = {0,0,0,0}, acc1 = {0,0,0,0};
    #pragma unroll
    for (int ks = 0; ks < 24; ++ks) {
      h16x8 a0 = *(const h16x8*)&UB[(li)*776      + ks*32 + lg*8];
      h16x8 a1 = *(const h16x8*)&UB[(16 + li)*776 + ks*32 + lg*8];
      h16x8 bk = *(const h16x8*)&Kp[(size_t)ks*16384 + (kcol + li)*32 + lg*8];
      acc0 = MFMA(a0, bk, acc0);
      acc1 = MFMA(a1, bk, acc1);
    }
    #pragma unroll
    for (int r = 0; r < 4; ++r) {
      int c = kcol + li;
      float v0 = acc0[r];
      if (v0 == 0.0f) v0 = -__builtin_inff();
      S[(lg*4 + r)*516 + c] = v0;
      float v1 = acc1[r];
      if (v1 == 0.0f) v1 = -__builtin_inff();
      S[(16 + lg*4 + r)*516 + c] = v1;
    }
  }
  for (int nf = nvf; nf < 8; ++nf) {
    int c = kbase + nf*16 + li;
    #pragma unroll
    for (int r = 0; r < 4; ++r) {
      S[(lg*4 + r)*516 + c] = -__builtin_inff();
      S[(16 + lg*4 + r)*516 + c] = -__builtin_inff();
    }
  }
  __syncthreads();
  {
    int row = t >> 3, ci = t & 7;
    float* Sr = &S[row*516];
    f32x4 mx4 = {-3e38f, -3e38f, -3e38f, -3e38f};
    #pragma unroll
    for (int j = 0; j < 16; ++j) {
      f32x4 v = *(const f32x4*)&Sr[ci*4 + j*32];
      #pragma unroll
      for (int k = 0; k < 4; ++k) mx4[k] = fmaxf(mx4[k], v[k]);
    }
    float mx = fmaxf(fmaxf(mx4[0], mx4[1]), fmaxf(mx4[2], mx4[3]));
    mx = fmaxf(mx, __shfl_xor(mx, 1));
    mx = fmaxf(mx, __shfl_xor(mx, 2));
    mx = fmaxf(mx, __shfl_xor(mx, 4));
    float sum = 0.0f;
    #pragma unroll
    for (int j = 0; j < 16; ++j) {
      f32x4 v = *(const f32x4*)&Sr[ci*4 + j*32];
      f32x4 e;
      #pragma unroll
      for (int k = 0; k < 4; ++k) e[k] = __expf(v[k] - mx);
      *(f32x4*)&Sr[ci*4 + j*32] = e;
      sum += e[0] + e[1] + e[2] + e[3];
    }
    sum += __shfl_xor(sum, 1);
    sum += __shfl_xor(sum, 2);
    sum += __shfl_xor(sum, 4);
    if (ci == 0) rowscale[row] = 1.0f / (sum > 0.0f ? sum : 1.0f);
  }
  __syncthreads();
  int n1 = (TL + 31) >> 5; n1 = n1 > 12 ? 12 : n1;
  int n2 = (IL + 31) >> 5; n2 = n2 > 4 ? 4 : n2;
  {
    f32x4 oacc[2][6] = {};
    auto pv = [&](int kt) {
      int k0 = kt * 32;
      h16x8 bv[6];
      #pragma unroll
      for (int n = 0; n < 6; ++n)
        bv[n] = *(const h16x8*)&Vp[(size_t)kt*24576 + (vh*384 + w*96 + n*16 + li)*32 + lg*8];
      #pragma unroll
      for (int m = 0; m < 2; ++m) {
        int row = m*16 + li;
        f32x4 p0 = *(const f32x4*)&S[row*516 + k0 + lg*8];
        f32x4 p1 = *(const f32x4*)&S[row*516 + k0 + lg*8 + 4];
        h16x8 pa;
        pa[0]=(h16)p0[0]; pa[1]=(h16)p0[1]; pa[2]=(h16)p0[2]; pa[3]=(h16)p0[3];
        pa[4]=(h16)p1[0]; pa[5]=(h16)p1[1]; pa[6]=(h16)p1[2]; pa[7]=(h16)p1[3];
        #pragma unroll
        for (int n = 0; n < 6; ++n)
          oacc[m][n] = MFMA(pa, bv[n], oacc[m][n]);
      }
    };
    for (int kt = 0; kt < n1; ++kt) pv(kt);
    for (int kt = 12; kt < 12 + n2; ++kt) pv(kt);
    #pragma unroll
    for (int n = 0; n < 6; ++n) {
      float cs = 0.0f;
      #pragma unroll
      for (int m = 0; m < 2; ++m)
        #pragma unroll
        for (int r = 0; r < 4; ++r)
          cs += oacc[m][n][r] * rowscale[m*16 + lg*4 + r];
      cs += __shfl_xor(cs, 16);
      cs += __shfl_xor(cs, 32);
      if (lg == 0) out[(size_t)b*768 + vh*384 + w*96 + n*16 + li] = cs * (1.0f/24.0f);
    }
  }
}

extern "C" void kernel_launch(void* const* d_in, const int* in_sizes, int n_in,
                              void* d_out, int out_size, void* d_ws, size_t ws_size,
                              hipStream_t stream)
{
  (void)in_sizes; (void)n_in;
  const float* text  = (const float*)d_in[0];
  const float* images= (const float*)d_in[1];
  const float* query = (const float*)d_in[2];
  const float* ln_g  = (const float*)d_in[3];
  const float* ln_b  = (const float*)d_in[4];
  const float* Wsq = (const float*)d_in[5];
  const float* bsq = (const float*)d_in[6];
  const float* Wiq = (const float*)d_in[7];
  const float* biq = (const float*)d_in[8];
  const float* Wsk = (const float*)d_in[9];
  const float* bsk = (const float*)d_in[10];
  const float* Wik = (const float*)d_in[11];
  const float* bik = (const float*)d_in[12];
  const float* Wsv = (const float*)d_in[13];
  const float* bsv = (const float*)d_in[14];
  const float* Wiv = (const float*)d_in[15];
  const float* biv = (const float*)d_in[16];
  const float* Wkp = (const float*)d_in[17];
  const float* bkp = (const float*)d_in[18];
  const float* Wvp = (const float*)d_in[19];
  const float* bvp = (const float*)d_in[20];
  const int* tlen = (const int*)d_in[21];
  const int* ilen = (const int*)d_in[22];
  const int* qlen = (const int*)d_in[23];

  const size_t NEED = 160694272 + 50331648;   // 211,025,920
  if (ws_size < NEED) {
    k_diag<<<dim3((out_size+255)/256), dim3(256), 0, stream>>>((float*)d_out, out_size, 1.0e6f);
    return;
  }
  h16* wb = (h16*)((char*)d_ws + 262144);
  const size_t WSZ = 589824;
  const size_t TSZ = (size_t)32768*768;
  h16* Qb = wb + 8*WSZ;
  h16* Kb = Qb + TSZ;
  h16* Vb = Kb + TSZ;
  h16* XNb = (h16*)((char*)d_ws + 160694272);

  dim3 blk(256);

  k_prep<<<dim3(4608 + 32768), blk, 0, stream>>>(
      Wsq, Wiq, Wsk, Wik, Wsv, Wiv, Wkp, Wvp, wb,
      text, images, ln_g, ln_b, XNb, tlen, ilen);

  k_gemmf2<0><<<dim3(4608), blk, 0, stream>>>(XNb, wb,
      bsq, biq, bsk, bik, bsv, biv, bkp, bvp, Qb, Kb, Vb, tlen, ilen);

  k_attn1<<<dim3(2048), blk, 0, stream>>>(Qb, Kb, Vb, XNb, tlen, ilen);

  k_gemmf2<2><<<dim3(3072), blk, 0, stream>>>(XNb, wb,
      bsq, biq, bsk, bik, bsv, biv, bkp, bvp, Kb, Vb, nullptr, tlen, ilen);

  k_attn2<<<dim3(128), blk, 0, stream>>>(query, Kb, Vb, qlen, tlen, ilen, (float*)d_out);
}